// Round 15
// baseline (281.487 us; speedup 1.0000x reference)
//
#include <hip/hip_runtime.h>
#include <hip/hip_bf16.h>

// ---------------------------------------------------------------------------
// Attention block: qkv = x@Wqkv ; flash causal attention ; out@Wout ; layernorm
// bf16 MFMA, fp32 accumulation.
// R14: R13 with the flag-clobber fixed: the flags memset is enqueued AFTER
//      gemm_qkv (wqkvT region is dead by then). R13 zeroed flags before
//      prep_all, which then overwrote them with weight data -> combine never
//      fired. Everything else identical to R13.
// ---------------------------------------------------------------------------

typedef __bf16 bf16_t;
typedef __bf16 bf16x8 __attribute__((ext_vector_type(8)));
typedef __bf16 bf16x4 __attribute__((ext_vector_type(4)));
typedef float  f32x4  __attribute__((ext_vector_type(4)));

#define DIMX   1024
#define HEADS  16
#define DHEAD  64
#define INNER  1024
#define SEQ    2048
#define BATCH  2
#define NROWS  (BATCH * SEQ)   // 4096
#define QKV_N  (3 * INNER)     // 3072
#define NQT    (SEQ / 64)      // 32 q-tiles of 64 rows
#define QK2SCALE 0.18033688011f   // 64^-0.5 * log2(e)

__device__ __forceinline__ bf16_t f2b(float f) { return (bf16_t)f; }

__device__ __forceinline__ float fexp2(float x) {
#if __has_builtin(__builtin_amdgcn_exp2f)
  return __builtin_amdgcn_exp2f(x);   // raw v_exp_f32
#else
  return exp2f(x);
#endif
}

// async global->LDS, 16B/lane. LDS dest = wave-uniform base + lane*16 (linear).
__device__ __forceinline__ void gload16(const bf16_t* g, bf16_t* s) {
  __builtin_amdgcn_global_load_lds(
      (const __attribute__((address_space(1))) unsigned int*)g,
      (__attribute__((address_space(3))) unsigned int*)s, 16, 0, 0);
}

__device__ __forceinline__ f32x4 mfma16(bf16x8 a, bf16x8 b, f32x4 c) {
  return __builtin_amdgcn_mfma_f32_16x16x32_bf16(a, b, c, 0, 0, 0);
}

// ---------------- prep: x->bf16 convert + both weight transposes ------------
__global__ __launch_bounds__(256)
void prep_all(const float* __restrict__ x, const float* __restrict__ w_qkv,
              const float* __restrict__ w_out, bf16_t* __restrict__ xb,
              bf16_t* __restrict__ wqkvT, bf16_t* __restrict__ woutT) {
  __shared__ float tile[32][33];
  const int bid = blockIdx.x;
  if (bid < 4096) {                       // convert x (fp32 -> bf16)
    const int i = bid * 256 + threadIdx.x;
    float4 v = *(const float4*)&x[(size_t)i * 4];
    bf16x4 o;
    o[0] = f2b(v.x); o[1] = f2b(v.y); o[2] = f2b(v.z); o[3] = f2b(v.w);
    *(bf16x4*)&xb[(size_t)i * 4] = o;
    return;
  }
  const float* in; bf16_t* out; int R, C, bx, by;
  if (bid < 4096 + 3072) {                // w_qkv [1024][3072] -> [3072][1024]
    const int t1 = bid - 4096;
    in = w_qkv; out = wqkvT; R = DIMX; C = QKV_N; bx = t1 % 96; by = t1 / 96;
  } else {                                // w_out [1024][1024] -> T
    const int t2 = bid - 7168;
    in = w_out; out = woutT; R = DIMX; C = DIMX; bx = t2 & 31; by = t2 >> 5;
  }
  const int c0 = bx * 32, r0 = by * 32;
  const int tx = threadIdx.x & 31, ty = threadIdx.x >> 5;   // 32 x 8
  #pragma unroll
  for (int i = 0; i < 32; i += 8)
    tile[ty + i][tx] = in[(size_t)(r0 + ty + i) * C + c0 + tx];
  __syncthreads();
  #pragma unroll
  for (int i = 0; i < 32; i += 8)
    out[(size_t)(c0 + ty + i) * R + r0 + tx] = f2b(tile[tx][ty + i]);
}

// ---------------- qkv GEMM with fused V-transpose ---------------------------
// C[M][N] = A[M][K] * Bt[N][K]^T, 128x128 tile, BK=64, 4 waves.
// Q/K tiles (n0<2048): bf16 store to qkv. V tiles (n0>=2048): transpose via
// the staging LDS (granule-XOR swizzle) and store C^T to vt, coalesced.
__global__ __launch_bounds__(256)
void gemm_qkv(const bf16_t* __restrict__ A, const bf16_t* __restrict__ Bt,
              bf16_t* __restrict__ C, bf16_t* __restrict__ vt) {
  constexpr int BK = 64, K = 1024, N = QKV_N;
  __shared__ bf16_t smem[2 * 128 * BK];   // As | Bs ; reused as transpose buf
  bf16_t* As = smem;
  bf16_t* Bs = smem + 128 * BK;
  const int t = threadIdx.x;
  const int w = t >> 6, l = t & 63, lo = l & 15, hi = l >> 4;
  const int nwg = gridDim.x * gridDim.y;            // 768, %8==0
  int flat = blockIdx.y * gridDim.x + blockIdx.x;
  flat = (flat & 7) * (nwg >> 3) + (flat >> 3);     // XCD swizzle (bijective)
  const int m0 = (flat / gridDim.x) * 128, n0 = (flat % gridDim.x) * 128;
  const int wm = (w >> 1) * 64, wn = (w & 1) * 64;
  const int sl  = l >> 3;
  const int sgc = ((l & 7) ^ sl) * 8;               // r7-only involution
  const int r7  = lo & 7;
  f32x4 acc[4][4] = {};
  for (int k0 = 0; k0 < K; k0 += BK) {
    #pragma unroll
    for (int c = 0; c < 4; ++c) {
      const int rb = w * 32 + c * 8;
      gload16(&A [(size_t)(m0 + rb + sl) * K + k0 + sgc], &As[rb * BK + l * 8]);
      gload16(&Bt[(size_t)(n0 + rb + sl) * K + k0 + sgc], &Bs[rb * BK + l * 8]);
    }
    __syncthreads();
    #pragma unroll
    for (int kk = 0; kk < 2; ++kk) {
      bf16x8 af[4], bfr[4];
      #pragma unroll
      for (int mi = 0; mi < 4; ++mi)
        af[mi] = *(const bf16x8*)&As[(wm + mi * 16 + lo) * BK +
                                     (((kk * 4 + hi) ^ r7) << 3)];
      #pragma unroll
      for (int nj = 0; nj < 4; ++nj)
        bfr[nj] = *(const bf16x8*)&Bs[(wn + nj * 16 + lo) * BK +
                                      (((kk * 4 + hi) ^ r7) << 3)];
      __builtin_amdgcn_s_setprio(1);
      #pragma unroll
      for (int mi = 0; mi < 4; ++mi)
        #pragma unroll
        for (int nj = 0; nj < 4; ++nj)
          acc[mi][nj] = mfma16(af[mi], bfr[nj], acc[mi][nj]);
      __builtin_amdgcn_s_setprio(0);
    }
    __syncthreads();
  }
  if (n0 < 2 * INNER) {
    // ---- Q/K tiles: normal bf16 store
    #pragma unroll
    for (int mi = 0; mi < 4; ++mi)
      #pragma unroll
      for (int nj = 0; nj < 4; ++nj)
        #pragma unroll
        for (int r = 0; r < 4; ++r)
          C[(size_t)(m0 + wm + mi * 16 + hi * 4 + r) * N +
            n0 + wn + nj * 16 + lo] = f2b(acc[mi][nj][r]);
  } else {
    // ---- V tiles: transpose through LDS, store C^T to vt.
    #pragma unroll
    for (int mi = 0; mi < 4; ++mi)
      #pragma unroll
      for (int nj = 0; nj < 4; ++nj) {
        const int cloc = wn + nj * 16 + lo;            // d-dim (col of C)
        const int g    = ((wm + mi * 16) >> 2) + hi;   // j-granule (row/4)
        bf16x4 pk;
        #pragma unroll
        for (int r = 0; r < 4; ++r) pk[r] = f2b(acc[mi][nj][r]);
        *(bf16x4*)((char*)smem + cloc * 256 + (((g ^ (cloc & 31))) << 3)) = pk;
      }
    __syncthreads();
    const int b  = m0 >> 11;           // m0 / SEQ
    const int j0 = m0 & (SEQ - 1);
    const int vrb = b * 1024 + (n0 - 2 * INNER);
    #pragma unroll
    for (int p = 0; p < 8; ++p) {
      const int c = p * 16 + w * 4 + hi;
      const int c31 = c & 31;
      bf16x4 a0 = *(const bf16x4*)((const char*)smem + c * 256 +
                                   (((2 * lo) ^ c31) << 3));
      bf16x4 a1 = *(const bf16x4*)((const char*)smem + c * 256 +
                                   (((2 * lo + 1) ^ c31) << 3));
      bf16x8 o;
      #pragma unroll
      for (int i = 0; i < 4; ++i) { o[i] = a0[i]; o[i + 4] = a1[i]; }
      *(bf16x8*)&vt[(size_t)(vrb + c) * SEQ + j0 + lo * 8] = o;
    }
  }
}

// ---------------- out-projection GEMM, split-K=2, bf16 partials -------------
__global__ __launch_bounds__(256)
void gemm_osk(const bf16_t* __restrict__ A0, const bf16_t* __restrict__ Bt0,
              bf16_t* __restrict__ P) {
  constexpr int BK = 64, KH = 512, LDA = 1024, N = DIMX, M = NROWS;
  __shared__ bf16_t smem[2 * 128 * BK];
  bf16_t* As = smem;
  bf16_t* Bs = smem + 128 * BK;
  const int ks = blockIdx.z;
  const bf16_t* A  = A0  + ks * KH;
  const bf16_t* Bt = Bt0 + ks * KH;
  bf16_t* Cp = P + (size_t)ks * M * N;
  const int t = threadIdx.x;
  const int w = t >> 6, l = t & 63, lo = l & 15, hi = l >> 4;
  const int nwg = gridDim.x * gridDim.y;            // 256, %8==0
  int flat = blockIdx.y * gridDim.x + blockIdx.x;
  flat = (flat & 7) * (nwg >> 3) + (flat >> 3);
  const int m0 = (flat / gridDim.x) * 128, n0 = (flat % gridDim.x) * 128;
  const int wm = (w >> 1) * 64, wn = (w & 1) * 64;
  const int sl  = l >> 3;
  const int sgc = ((l & 7) ^ sl) * 8;
  const int r7  = lo & 7;
  f32x4 acc[4][4] = {};
  for (int k0 = 0; k0 < KH; k0 += BK) {
    #pragma unroll
    for (int c = 0; c < 4; ++c) {
      const int rb = w * 32 + c * 8;
      gload16(&A [(size_t)(m0 + rb + sl) * LDA + k0 + sgc], &As[rb * BK + l * 8]);
      gload16(&Bt[(size_t)(n0 + rb + sl) * LDA + k0 + sgc], &Bs[rb * BK + l * 8]);
    }
    __syncthreads();
    #pragma unroll
    for (int kk = 0; kk < 2; ++kk) {
      bf16x8 af[4], bfr[4];
      #pragma unroll
      for (int mi = 0; mi < 4; ++mi)
        af[mi] = *(const bf16x8*)&As[(wm + mi * 16 + lo) * BK +
                                     (((kk * 4 + hi) ^ r7) << 3)];
      #pragma unroll
      for (int nj = 0; nj < 4; ++nj)
        bfr[nj] = *(const bf16x8*)&Bs[(wn + nj * 16 + lo) * BK +
                                      (((kk * 4 + hi) ^ r7) << 3)];
      __builtin_amdgcn_s_setprio(1);
      #pragma unroll
      for (int mi = 0; mi < 4; ++mi)
        #pragma unroll
        for (int nj = 0; nj < 4; ++nj)
          acc[mi][nj] = mfma16(af[mi], bfr[nj], acc[mi][nj]);
      __builtin_amdgcn_s_setprio(0);
    }
    __syncthreads();
  }
  #pragma unroll
  for (int mi = 0; mi < 4; ++mi)
    #pragma unroll
    for (int nj = 0; nj < 4; ++nj)
      #pragma unroll
      for (int r = 0; r < 4; ++r)
        Cp[(size_t)(m0 + wm + mi * 16 + hi * 4 + r) * N +
           n0 + wn + nj * 16 + lo] = f2b(acc[mi][nj][r]);
}

// ---------------- flash causal attention + fused combine --------------------
// Balanced pair-split (1024 blocks). Swapped QK^T; PV via K=32 MFMA over
// paired jb's. l-sum on the matrix pipe. Per-(bh,tb) flag: the second
// finisher combines the two partials and stores normalized rows.
__global__ __launch_bounds__(256, 4)
void attn_fa13(const bf16_t* __restrict__ qkv, const bf16_t* __restrict__ vt,
               bf16_t* __restrict__ attn_out, bf16_t* __restrict__ pacc,
               float* __restrict__ plsum, int* __restrict__ flags) {
  const int bx  = blockIdx.x;           // 1024
  const int xcd = bx & 7, idx = bx >> 3;
  const int bh  = xcd * 4 + (idx & 3);
  const int ta  = (idx >> 2) & 15;
  const int half = idx >> 6;            // 0 = X, 1 = Y
  const int tb  = NQT - 1 - ta;
  const int b = bh >> 4, h = bh & 15;
  const int t = threadIdx.x, w = t >> 6, l = t & 63, lo = l & 15, hi = l >> 4;

  __shared__ bf16_t Ks[2][64 * 64];     // 16 KB
  __shared__ bf16_t Vs[2][64 * 64];     // 16 KB

  const int srow = l >> 3;
  const int sgc  = ((l & 7) ^ srow) * 8;      // r7-only involution
  const size_t kgbase = (size_t)(b * SEQ) * QKV_N + INNER + h * 64;
  const size_t vgbase = (size_t)bh * 64 * SEQ;

  auto STAGE = [&](int ti, int buf) {
    const int j0 = ti * 64;
    #pragma unroll
    for (int c = 0; c < 2; ++c) {
      const int rb = w * 16 + c * 8;
      gload16(&qkv[kgbase + (size_t)(j0 + rb + srow) * QKV_N + sgc],
              &Ks[buf][rb * 64]);
      gload16(&vt[vgbase + (size_t)(rb + srow) * SEQ + j0 + sgc],
              &Vs[buf][rb * 64]);
    }
  };

  const int r7 = lo & 7;
  bf16x8 vone8;
  #pragma unroll
  for (int i = 0; i < 8; ++i) vone8[i] = f2b(1.0f);
  f32x4 acc[4];
  f32x4 acc_l;   // row hi*4+r: sum_j P[q=row][j], replicated across lo lanes

  auto SEG = [&](const int qt, const int t0, const int t1, const bool dmask) {
    const size_t qb = (size_t)(b * SEQ + qt * 64 + w * 16 + lo) * QKV_N + h * 64;
    bf16x8 qf0 = *(const bf16x8*)&qkv[qb + hi * 8];
    bf16x8 qf1 = *(const bf16x8*)&qkv[qb + 32 + hi * 8];
    #pragma unroll
    for (int i = 0; i < 8; ++i) {
      qf0[i] = f2b((float)qf0[i] * QK2SCALE);
      qf1[i] = f2b((float)qf1[i] * QK2SCALE);
    }
    const f32x4 fz = {};
    acc[0] = fz; acc[1] = fz; acc[2] = fz; acc[3] = fz;
    acc_l = fz;
    const int qrow = qt * 64 + w * 16 + lo;

    STAGE(t0, 0);
    for (int ti = t0; ti <= t1; ++ti) {
      const int buf = (ti - t0) & 1;
      __syncthreads();
      if (ti + 1 <= t1) STAGE(ti + 1, buf ^ 1);  // fly across compute
      const bool mB = dmask && (ti == t1);
      __builtin_amdgcn_s_setprio(1);
      #pragma unroll
      for (int pr = 0; pr < 2; ++pr) {           // jb pairs (0,1), (2,3)
        const int jb0 = pr * 2;
        if (!(mB && jb0 > w)) {
          bf16x8 pa;
          #pragma unroll
          for (int q = 0; q < 2; ++q) {
            const int jb = jb0 + q;
            f32x4 z = fz;
            if (!(mB && jb > w)) {
              const bf16_t* kp = &Ks[buf][(jb * 16 + lo) * 64];
              bf16x8 kf0 = *(const bf16x8*)&kp[(hi ^ r7) << 3];
              bf16x8 kf1 = *(const bf16x8*)&kp[((hi + 4) ^ r7) << 3];
              z = mfma16(kf0, qf0, z);
              z = mfma16(kf1, qf1, z);
            }
            #pragma unroll
            for (int r = 0; r < 4; ++r) {
              float pe = fexp2(z[r]);
              if (mB) {
                const int jglob = ti * 64 + jb * 16 + hi * 4 + r;
                if (jglob > qrow) pe = 0.f;      // causal
              }
              pa[q * 4 + r] = f2b(pe);
            }
          }
          #pragma unroll
          for (int dj = 0; dj < 4; ++dj) {
            const bf16_t* vp = &Vs[buf][(dj * 16 + lo) * 64];
            bf16x4 va = *(const bf16x4*)&vp[
                (((2 * jb0 + (hi >> 1)) ^ r7) << 3) + ((hi & 1) << 2)];
            bf16x4 vb = *(const bf16x4*)&vp[
                (((2 * jb0 + 2 + (hi >> 1)) ^ r7) << 3) + ((hi & 1) << 2)];
            bf16x8 vf;
            #pragma unroll
            for (int i = 0; i < 4; ++i) { vf[i] = va[i]; vf[i + 4] = vb[i]; }
            acc[dj] = mfma16(pa, vf, acc[dj]);
          }
          acc_l = mfma16(pa, vone8, acc_l);
        }
      }
      __builtin_amdgcn_s_setprio(0);
    }
    __syncthreads();
  };

  const int tloc = bh * 16 + (tb - 16);     // combine slot, 0..511
  const int prb  = tloc * 64;

  if (half == 0) {
    SEG(ta, 0, ta, true);
    #pragma unroll
    for (int r = 0; r < 4; ++r) {
      const float lr = 1.f / acc_l[r];
      #pragma unroll
      for (int dj = 0; dj < 4; ++dj)
        attn_out[(size_t)(b * SEQ + ta * 64 + w * 16 + hi * 4 + r) * INNER +
                 h * 64 + dj * 16 + lo] = f2b(acc[dj][r] * lr);
    }
    SEG(tb, 0, 15 - ta, false);
    #pragma unroll
    for (int dj = 0; dj < 4; ++dj)
      #pragma unroll
      for (int r = 0; r < 4; ++r)
        pacc[(size_t)(prb + w * 16 + hi * 4 + r) * 64 + dj * 16 + lo] =
            f2b(acc[dj][r]);
    if (lo == 0) {
      #pragma unroll
      for (int r = 0; r < 4; ++r)
        plsum[prb + w * 16 + hi * 4 + r] = acc_l[r];
    }
  } else {
    SEG(tb, 16 - ta, tb, true);
    #pragma unroll
    for (int dj = 0; dj < 4; ++dj)
      #pragma unroll
      for (int r = 0; r < 4; ++r)
        pacc[2097152 + (size_t)(prb + w * 16 + hi * 4 + r) * 64 + dj * 16 + lo] =
            f2b(acc[dj][r]);
    if (lo == 0) {
      #pragma unroll
      for (int r = 0; r < 4; ++r)
        plsum[32768 + prb + w * 16 + hi * 4 + r] = acc_l[r];
    }
  }

  // ---- fused combine: second finisher of this (bh,tb) pair does it --------
  __threadfence();                         // publish partial (device scope)
  int* s_old = (int*)&Ks[0][0];            // LDS is dead now
  __syncthreads();                         // (also orders the s_old reuse)
  if (t == 0) *s_old = atomicAdd(&flags[tloc], 1);
  __syncthreads();
  if (*s_old == 1) {
    __threadfence();                       // acquire the other half's data
    #pragma unroll
    for (int i = 0; i < 2; ++i) {
      const int item = t * 2 + i;          // 0..511 : 64 rows x 8 chunks
      const int qr = item >> 3, d8 = item & 7;
      const size_t rw = (size_t)(prb + qr);
      bf16x8 xa = *(const bf16x8*)&pacc[rw * 64 + d8 * 8];
      bf16x8 ya = *(const bf16x8*)&pacc[2097152 + rw * 64 + d8 * 8];
      const float inv = 1.f / (plsum[prb + qr] + plsum[32768 + prb + qr]);
      bf16x8 o;
      #pragma unroll
      for (int k = 0; k < 8; ++k)
        o[k] = f2b(((float)xa[k] + (float)ya[k]) * inv);
      *(bf16x8*)&attn_out[(size_t)(b * SEQ + tb * 64 + qr) * INNER +
                          h * 64 + d8 * 8] = o;
    }
  }
}

// ---------------- layernorm over summed bf16 split-K partials ---------------
__global__ __launch_bounds__(256)
void layernorm_skb(const bf16_t* __restrict__ p0, const bf16_t* __restrict__ p1,
                   const float* __restrict__ g, float* __restrict__ out) {
  const int row = blockIdx.x;
  const int c = threadIdx.x * 4;
  bf16x4 a4 = *(const bf16x4*)&p0[(size_t)row * DIMX + c];
  bf16x4 b4 = *(const bf16x4*)&p1[(size_t)row * DIMX + c];
  const float vx = (float)a4[0] + (float)b4[0];
  const float vy = (float)a4[1] + (float)b4[1];
  const float vz = (float)a4[2] + (float)b4[2];
  const float vw = (float)a4[3] + (float)b4[3];
  float s = vx + vy + vz + vw;
  float q = vx * vx + vy * vy + vz * vz + vw * vw;
  #pragma unroll
  for (int o = 32; o > 0; o >>= 1) {
    s += __shfl_down(s, o);
    q += __shfl_down(q, o);
  }
  __shared__ float rs[4], rq[4];
  const int wid = threadIdx.x >> 6;
  if ((threadIdx.x & 63) == 0) { rs[wid] = s; rq[wid] = q; }
  __syncthreads();
  s = rs[0] + rs[1] + rs[2] + rs[3];
  q = rq[0] + rq[1] + rq[2] + rq[3];
  const float mean = s * (1.f / DIMX);
  const float var  = q * (1.f / DIMX) - mean * mean;
  const float inv  = rsqrtf(var + 1e-5f);
  float4 gv = *(const float4*)&g[c];
  float4 o4;
  o4.x = (vx - mean) * inv * gv.x;
  o4.y = (vy - mean) * inv * gv.y;
  o4.z = (vz - mean) * inv * gv.z;
  o4.w = (vw - mean) * inv * gv.w;
  *(float4*)&out[(size_t)row * DIMX + c] = o4;
}

// ---------------------------------------------------------------------------
extern "C" void kernel_launch(void* const* d_in, const int* in_sizes, int n_in,
                              void* d_out, int out_size, void* d_ws, size_t ws_size,
                              hipStream_t stream) {
  const float* x     = (const float*)d_in[0];
  // d_in[1] = mask: all-true in this problem; causal handled in-kernel.
  const float* w_qkv = (const float*)d_in[2];
  const float* w_out = (const float*)d_in[3];
  const float* g     = (const float*)d_in[4];

  char* ws = (char*)d_ws;
  const size_t MB = 1024 * 1024;
  bf16_t* xb     = (bf16_t*)(ws);              //  8 MB  [4096][1024] (pre-attn)
  bf16_t* wqkvT  = (bf16_t*)(ws + 8 * MB);     //  6 MB  [3072][1024] (pre-attn)
  bf16_t* woutT  = (bf16_t*)(ws + 14 * MB);    //  2 MB  [1024][1024]
  bf16_t* qkv    = (bf16_t*)(ws + 16 * MB);    // 24 MB  [4096][3072] (Q,K used)
  bf16_t* vt     = (bf16_t*)(ws + 40 * MB);    //  8 MB  [32*64][2048]
  bf16_t* attn_o = (bf16_t*)(ws + 48 * MB);    //  8 MB  [4096][1024]
  // aliases (regions dead by the time they're used):
  bf16_t* pacc   = (bf16_t*)(ws);              //  8 MB over xb (attn phase)
  float*  plsum  = (float*) (ws + 8 * MB);     // 256 KB over wqkvT (attn phase)
  int*    flags  = (int*)   (ws + 8 * MB + 262144);  // 2 KB over wqkvT
  bf16_t* partP  = (bf16_t*)(ws + 16 * MB);    // 16 MB over qkv (post-attn)

  prep_all<<<8192, 256, 0, stream>>>(x, w_qkv, w_out, xb, wqkvT, woutT);

  gemm_qkv<<<dim3(QKV_N / 128, NROWS / 128), 256, 0, stream>>>(
      xb, wqkvT, qkv, vt);

  // zero flags AFTER gemm_qkv: wqkvT (which flags alias) is dead only now.
  hipMemsetAsync(flags, 0, 512 * sizeof(int), stream);

  attn_fa13<<<dim3(1024), 256, 0, stream>>>(qkv, vt, attn_o, pacc, plsum, flags);

  gemm_osk<<<dim3(DIMX / 128, NROWS / 128, 2), 256, 0, stream>>>(
      attn_o, woutT, partP);

  layernorm_skb<<<NROWS, 256, 0, stream>>>(
      partP, partP + (size_t)NROWS * DIMX, g, (float*)d_out);
}

// Round 16
// 103.073 us; speedup vs baseline: 2.7310x; 2.7310x over previous
//
#include <hip/hip_runtime.h>
#include <hip/hip_bf16.h>

// ---------------------------------------------------------------------------
// Attention block: qkv = x@Wqkv ; flash causal attention ; out@Wout ; layernorm
// bf16 MFMA, fp32 accumulation.
// R15: REVERT the fused-combine fences (R14: device-scope __threadfence =
//      L2 writeback storm on 8 non-coherent XCDs, 6x attn regression).
//      Separate combine kernel (R12 structure) restored; KEEP bf16 split-K
//      partials (osk write + LN read halved vs fp32).
// ---------------------------------------------------------------------------

typedef __bf16 bf16_t;
typedef __bf16 bf16x8 __attribute__((ext_vector_type(8)));
typedef __bf16 bf16x4 __attribute__((ext_vector_type(4)));
typedef float  f32x4  __attribute__((ext_vector_type(4)));

#define DIMX   1024
#define HEADS  16
#define DHEAD  64
#define INNER  1024
#define SEQ    2048
#define BATCH  2
#define NROWS  (BATCH * SEQ)   // 4096
#define QKV_N  (3 * INNER)     // 3072
#define NQT    (SEQ / 64)      // 32 q-tiles of 64 rows
#define QK2SCALE 0.18033688011f   // 64^-0.5 * log2(e)

__device__ __forceinline__ bf16_t f2b(float f) { return (bf16_t)f; }

__device__ __forceinline__ float fexp2(float x) {
#if __has_builtin(__builtin_amdgcn_exp2f)
  return __builtin_amdgcn_exp2f(x);   // raw v_exp_f32
#else
  return exp2f(x);
#endif
}

// async global->LDS, 16B/lane. LDS dest = wave-uniform base + lane*16 (linear).
__device__ __forceinline__ void gload16(const bf16_t* g, bf16_t* s) {
  __builtin_amdgcn_global_load_lds(
      (const __attribute__((address_space(1))) unsigned int*)g,
      (__attribute__((address_space(3))) unsigned int*)s, 16, 0, 0);
}

__device__ __forceinline__ f32x4 mfma16(bf16x8 a, bf16x8 b, f32x4 c) {
  return __builtin_amdgcn_mfma_f32_16x16x32_bf16(a, b, c, 0, 0, 0);
}

// ---------------- prep: x->bf16 convert + both weight transposes ------------
__global__ __launch_bounds__(256)
void prep_all(const float* __restrict__ x, const float* __restrict__ w_qkv,
              const float* __restrict__ w_out, bf16_t* __restrict__ xb,
              bf16_t* __restrict__ wqkvT, bf16_t* __restrict__ woutT) {
  __shared__ float tile[32][33];
  const int bid = blockIdx.x;
  if (bid < 4096) {                       // convert x (fp32 -> bf16)
    const int i = bid * 256 + threadIdx.x;
    float4 v = *(const float4*)&x[(size_t)i * 4];
    bf16x4 o;
    o[0] = f2b(v.x); o[1] = f2b(v.y); o[2] = f2b(v.z); o[3] = f2b(v.w);
    *(bf16x4*)&xb[(size_t)i * 4] = o;
    return;
  }
  const float* in; bf16_t* out; int R, C, bx, by;
  if (bid < 4096 + 3072) {                // w_qkv [1024][3072] -> [3072][1024]
    const int t1 = bid - 4096;
    in = w_qkv; out = wqkvT; R = DIMX; C = QKV_N; bx = t1 % 96; by = t1 / 96;
  } else {                                // w_out [1024][1024] -> T
    const int t2 = bid - 7168;
    in = w_out; out = woutT; R = DIMX; C = DIMX; bx = t2 & 31; by = t2 >> 5;
  }
  const int c0 = bx * 32, r0 = by * 32;
  const int tx = threadIdx.x & 31, ty = threadIdx.x >> 5;   // 32 x 8
  #pragma unroll
  for (int i = 0; i < 32; i += 8)
    tile[ty + i][tx] = in[(size_t)(r0 + ty + i) * C + c0 + tx];
  __syncthreads();
  #pragma unroll
  for (int i = 0; i < 32; i += 8)
    out[(size_t)(c0 + ty + i) * R + r0 + tx] = f2b(tile[tx][ty + i]);
}

// ---------------- qkv GEMM with fused V-transpose ---------------------------
// C[M][N] = A[M][K] * Bt[N][K]^T, 128x128 tile, BK=64, 4 waves.
// Q/K tiles (n0<2048): bf16 store to qkv. V tiles (n0>=2048): transpose via
// the staging LDS (granule-XOR swizzle) and store C^T to vt, coalesced.
__global__ __launch_bounds__(256)
void gemm_qkv(const bf16_t* __restrict__ A, const bf16_t* __restrict__ Bt,
              bf16_t* __restrict__ C, bf16_t* __restrict__ vt) {
  constexpr int BK = 64, K = 1024, N = QKV_N;
  __shared__ bf16_t smem[2 * 128 * BK];   // As | Bs ; reused as transpose buf
  bf16_t* As = smem;
  bf16_t* Bs = smem + 128 * BK;
  const int t = threadIdx.x;
  const int w = t >> 6, l = t & 63, lo = l & 15, hi = l >> 4;
  const int nwg = gridDim.x * gridDim.y;            // 768, %8==0
  int flat = blockIdx.y * gridDim.x + blockIdx.x;
  flat = (flat & 7) * (nwg >> 3) + (flat >> 3);     // XCD swizzle (bijective)
  const int m0 = (flat / gridDim.x) * 128, n0 = (flat % gridDim.x) * 128;
  const int wm = (w >> 1) * 64, wn = (w & 1) * 64;
  const int sl  = l >> 3;
  const int sgc = ((l & 7) ^ sl) * 8;               // r7-only involution
  const int r7  = lo & 7;
  f32x4 acc[4][4] = {};
  for (int k0 = 0; k0 < K; k0 += BK) {
    #pragma unroll
    for (int c = 0; c < 4; ++c) {
      const int rb = w * 32 + c * 8;
      gload16(&A [(size_t)(m0 + rb + sl) * K + k0 + sgc], &As[rb * BK + l * 8]);
      gload16(&Bt[(size_t)(n0 + rb + sl) * K + k0 + sgc], &Bs[rb * BK + l * 8]);
    }
    __syncthreads();
    #pragma unroll
    for (int kk = 0; kk < 2; ++kk) {
      bf16x8 af[4], bfr[4];
      #pragma unroll
      for (int mi = 0; mi < 4; ++mi)
        af[mi] = *(const bf16x8*)&As[(wm + mi * 16 + lo) * BK +
                                     (((kk * 4 + hi) ^ r7) << 3)];
      #pragma unroll
      for (int nj = 0; nj < 4; ++nj)
        bfr[nj] = *(const bf16x8*)&Bs[(wn + nj * 16 + lo) * BK +
                                      (((kk * 4 + hi) ^ r7) << 3)];
      __builtin_amdgcn_s_setprio(1);
      #pragma unroll
      for (int mi = 0; mi < 4; ++mi)
        #pragma unroll
        for (int nj = 0; nj < 4; ++nj)
          acc[mi][nj] = mfma16(af[mi], bfr[nj], acc[mi][nj]);
      __builtin_amdgcn_s_setprio(0);
    }
    __syncthreads();
  }
  if (n0 < 2 * INNER) {
    // ---- Q/K tiles: normal bf16 store
    #pragma unroll
    for (int mi = 0; mi < 4; ++mi)
      #pragma unroll
      for (int nj = 0; nj < 4; ++nj)
        #pragma unroll
        for (int r = 0; r < 4; ++r)
          C[(size_t)(m0 + wm + mi * 16 + hi * 4 + r) * N +
            n0 + wn + nj * 16 + lo] = f2b(acc[mi][nj][r]);
  } else {
    // ---- V tiles: transpose through LDS, store C^T to vt.
    #pragma unroll
    for (int mi = 0; mi < 4; ++mi)
      #pragma unroll
      for (int nj = 0; nj < 4; ++nj) {
        const int cloc = wn + nj * 16 + lo;            // d-dim (col of C)
        const int g    = ((wm + mi * 16) >> 2) + hi;   // j-granule (row/4)
        bf16x4 pk;
        #pragma unroll
        for (int r = 0; r < 4; ++r) pk[r] = f2b(acc[mi][nj][r]);
        *(bf16x4*)((char*)smem + cloc * 256 + (((g ^ (cloc & 31))) << 3)) = pk;
      }
    __syncthreads();
    const int b  = m0 >> 11;           // m0 / SEQ
    const int j0 = m0 & (SEQ - 1);
    const int vrb = b * 1024 + (n0 - 2 * INNER);
    #pragma unroll
    for (int p = 0; p < 8; ++p) {
      const int c = p * 16 + w * 4 + hi;
      const int c31 = c & 31;
      bf16x4 a0 = *(const bf16x4*)((const char*)smem + c * 256 +
                                   (((2 * lo) ^ c31) << 3));
      bf16x4 a1 = *(const bf16x4*)((const char*)smem + c * 256 +
                                   (((2 * lo + 1) ^ c31) << 3));
      bf16x8 o;
      #pragma unroll
      for (int i = 0; i < 4; ++i) { o[i] = a0[i]; o[i + 4] = a1[i]; }
      *(bf16x8*)&vt[(size_t)(vrb + c) * SEQ + j0 + lo * 8] = o;
    }
  }
}

// ---------------- out-projection GEMM, split-K=2, bf16 partials -------------
__global__ __launch_bounds__(256)
void gemm_osk(const bf16_t* __restrict__ A0, const bf16_t* __restrict__ Bt0,
              bf16_t* __restrict__ P) {
  constexpr int BK = 64, KH = 512, LDA = 1024, N = DIMX, M = NROWS;
  __shared__ bf16_t smem[2 * 128 * BK];
  bf16_t* As = smem;
  bf16_t* Bs = smem + 128 * BK;
  const int ks = blockIdx.z;
  const bf16_t* A  = A0  + ks * KH;
  const bf16_t* Bt = Bt0 + ks * KH;
  bf16_t* Cp = P + (size_t)ks * M * N;
  const int t = threadIdx.x;
  const int w = t >> 6, l = t & 63, lo = l & 15, hi = l >> 4;
  const int nwg = gridDim.x * gridDim.y;            // 256, %8==0
  int flat = blockIdx.y * gridDim.x + blockIdx.x;
  flat = (flat & 7) * (nwg >> 3) + (flat >> 3);
  const int m0 = (flat / gridDim.x) * 128, n0 = (flat % gridDim.x) * 128;
  const int wm = (w >> 1) * 64, wn = (w & 1) * 64;
  const int sl  = l >> 3;
  const int sgc = ((l & 7) ^ sl) * 8;
  const int r7  = lo & 7;
  f32x4 acc[4][4] = {};
  for (int k0 = 0; k0 < KH; k0 += BK) {
    #pragma unroll
    for (int c = 0; c < 4; ++c) {
      const int rb = w * 32 + c * 8;
      gload16(&A [(size_t)(m0 + rb + sl) * LDA + k0 + sgc], &As[rb * BK + l * 8]);
      gload16(&Bt[(size_t)(n0 + rb + sl) * LDA + k0 + sgc], &Bs[rb * BK + l * 8]);
    }
    __syncthreads();
    #pragma unroll
    for (int kk = 0; kk < 2; ++kk) {
      bf16x8 af[4], bfr[4];
      #pragma unroll
      for (int mi = 0; mi < 4; ++mi)
        af[mi] = *(const bf16x8*)&As[(wm + mi * 16 + lo) * BK +
                                     (((kk * 4 + hi) ^ r7) << 3)];
      #pragma unroll
      for (int nj = 0; nj < 4; ++nj)
        bfr[nj] = *(const bf16x8*)&Bs[(wn + nj * 16 + lo) * BK +
                                      (((kk * 4 + hi) ^ r7) << 3)];
      __builtin_amdgcn_s_setprio(1);
      #pragma unroll
      for (int mi = 0; mi < 4; ++mi)
        #pragma unroll
        for (int nj = 0; nj < 4; ++nj)
          acc[mi][nj] = mfma16(af[mi], bfr[nj], acc[mi][nj]);
      __builtin_amdgcn_s_setprio(0);
    }
    __syncthreads();
  }
  #pragma unroll
  for (int mi = 0; mi < 4; ++mi)
    #pragma unroll
    for (int nj = 0; nj < 4; ++nj)
      #pragma unroll
      for (int r = 0; r < 4; ++r)
        Cp[(size_t)(m0 + wm + mi * 16 + hi * 4 + r) * N +
           n0 + wn + nj * 16 + lo] = f2b(acc[mi][nj][r]);
}

// ---------------- flash causal attention (R11/R12 structure) ----------------
// Balanced pair-split (1024 blocks). Swapped QK^T; PV via K=32 MFMA over
// paired jb's. l-sum on the matrix pipe. Partials to pacc/plsum; separate
// combine kernel (NO device-scope fences in-kernel).
__global__ __launch_bounds__(256, 4)
void attn_fa12(const bf16_t* __restrict__ qkv, const bf16_t* __restrict__ vt,
               bf16_t* __restrict__ attn_out, bf16_t* __restrict__ pacc,
               float* __restrict__ plsum) {
  const int bx  = blockIdx.x;           // 1024
  const int xcd = bx & 7, idx = bx >> 3;
  const int bh  = xcd * 4 + (idx & 3);
  const int ta  = (idx >> 2) & 15;
  const int half = idx >> 6;            // 0 = X, 1 = Y
  const int tb  = NQT - 1 - ta;
  const int b = bh >> 4, h = bh & 15;
  const int t = threadIdx.x, w = t >> 6, l = t & 63, lo = l & 15, hi = l >> 4;

  __shared__ bf16_t Ks[2][64 * 64];     // 16 KB
  __shared__ bf16_t Vs[2][64 * 64];     // 16 KB

  const int srow = l >> 3;
  const int sgc  = ((l & 7) ^ srow) * 8;      // r7-only involution
  const size_t kgbase = (size_t)(b * SEQ) * QKV_N + INNER + h * 64;
  const size_t vgbase = (size_t)bh * 64 * SEQ;

  auto STAGE = [&](int ti, int buf) {
    const int j0 = ti * 64;
    #pragma unroll
    for (int c = 0; c < 2; ++c) {
      const int rb = w * 16 + c * 8;
      gload16(&qkv[kgbase + (size_t)(j0 + rb + srow) * QKV_N + sgc],
              &Ks[buf][rb * 64]);
      gload16(&vt[vgbase + (size_t)(rb + srow) * SEQ + j0 + sgc],
              &Vs[buf][rb * 64]);
    }
  };

  const int r7 = lo & 7;
  bf16x8 vone8;
  #pragma unroll
  for (int i = 0; i < 8; ++i) vone8[i] = f2b(1.0f);
  f32x4 acc[4];
  f32x4 acc_l;   // row hi*4+r: sum_j P[q=row][j], replicated across lo lanes

  auto SEG = [&](const int qt, const int t0, const int t1, const bool dmask) {
    const size_t qb = (size_t)(b * SEQ + qt * 64 + w * 16 + lo) * QKV_N + h * 64;
    bf16x8 qf0 = *(const bf16x8*)&qkv[qb + hi * 8];
    bf16x8 qf1 = *(const bf16x8*)&qkv[qb + 32 + hi * 8];
    #pragma unroll
    for (int i = 0; i < 8; ++i) {
      qf0[i] = f2b((float)qf0[i] * QK2SCALE);
      qf1[i] = f2b((float)qf1[i] * QK2SCALE);
    }
    const f32x4 fz = {};
    acc[0] = fz; acc[1] = fz; acc[2] = fz; acc[3] = fz;
    acc_l = fz;
    const int qrow = qt * 64 + w * 16 + lo;

    STAGE(t0, 0);
    for (int ti = t0; ti <= t1; ++ti) {
      const int buf = (ti - t0) & 1;
      __syncthreads();
      if (ti + 1 <= t1) STAGE(ti + 1, buf ^ 1);  // fly across compute
      const bool mB = dmask && (ti == t1);
      __builtin_amdgcn_s_setprio(1);
      #pragma unroll
      for (int pr = 0; pr < 2; ++pr) {           // jb pairs (0,1), (2,3)
        const int jb0 = pr * 2;
        if (!(mB && jb0 > w)) {
          bf16x8 pa;
          #pragma unroll
          for (int q = 0; q < 2; ++q) {
            const int jb = jb0 + q;
            f32x4 z = fz;
            if (!(mB && jb > w)) {
              const bf16_t* kp = &Ks[buf][(jb * 16 + lo) * 64];
              bf16x8 kf0 = *(const bf16x8*)&kp[(hi ^ r7) << 3];
              bf16x8 kf1 = *(const bf16x8*)&kp[((hi + 4) ^ r7) << 3];
              z = mfma16(kf0, qf0, z);
              z = mfma16(kf1, qf1, z);
            }
            #pragma unroll
            for (int r = 0; r < 4; ++r) {
              float pe = fexp2(z[r]);
              if (mB) {
                const int jglob = ti * 64 + jb * 16 + hi * 4 + r;
                if (jglob > qrow) pe = 0.f;      // causal
              }
              pa[q * 4 + r] = f2b(pe);
            }
          }
          #pragma unroll
          for (int dj = 0; dj < 4; ++dj) {
            const bf16_t* vp = &Vs[buf][(dj * 16 + lo) * 64];
            bf16x4 va = *(const bf16x4*)&vp[
                (((2 * jb0 + (hi >> 1)) ^ r7) << 3) + ((hi & 1) << 2)];
            bf16x4 vb = *(const bf16x4*)&vp[
                (((2 * jb0 + 2 + (hi >> 1)) ^ r7) << 3) + ((hi & 1) << 2)];
            bf16x8 vf;
            #pragma unroll
            for (int i = 0; i < 4; ++i) { vf[i] = va[i]; vf[i + 4] = vb[i]; }
            acc[dj] = mfma16(pa, vf, acc[dj]);
          }
          acc_l = mfma16(pa, vone8, acc_l);
        }
      }
      __builtin_amdgcn_s_setprio(0);
    }
    __syncthreads();
  };

  const int prb = (bh * 16 + (tb - 16)) * 64;

  if (half == 0) {
    SEG(ta, 0, ta, true);
    #pragma unroll
    for (int r = 0; r < 4; ++r) {
      const float lr = 1.f / acc_l[r];
      #pragma unroll
      for (int dj = 0; dj < 4; ++dj)
        attn_out[(size_t)(b * SEQ + ta * 64 + w * 16 + hi * 4 + r) * INNER +
                 h * 64 + dj * 16 + lo] = f2b(acc[dj][r] * lr);
    }
    SEG(tb, 0, 15 - ta, false);
    #pragma unroll
    for (int dj = 0; dj < 4; ++dj)
      #pragma unroll
      for (int r = 0; r < 4; ++r)
        pacc[(size_t)(prb + w * 16 + hi * 4 + r) * 64 + dj * 16 + lo] =
            f2b(acc[dj][r]);
    if (lo == 0) {
      #pragma unroll
      for (int r = 0; r < 4; ++r)
        plsum[prb + w * 16 + hi * 4 + r] = acc_l[r];
    }
  } else {
    SEG(tb, 16 - ta, tb, true);
    #pragma unroll
    for (int dj = 0; dj < 4; ++dj)
      #pragma unroll
      for (int r = 0; r < 4; ++r)
        pacc[2097152 + (size_t)(prb + w * 16 + hi * 4 + r) * 64 + dj * 16 + lo] =
            f2b(acc[dj][r]);
    if (lo == 0) {
      #pragma unroll
      for (int r = 0; r < 4; ++r)
        plsum[32768 + prb + w * 16 + hi * 4 + r] = acc_l[r];
    }
  }
}

// ---------------- combine the two tb partials -------------------------------
__global__ __launch_bounds__(256)
void attn_combine(const bf16_t* __restrict__ pacc, const float* __restrict__ plsum,
                  bf16_t* __restrict__ attn_out) {
  const int g = blockIdx.x * 256 + threadIdx.x;   // 262144
  const int d8 = g & 7;
  const int row = g >> 3;                         // [bh][qt-16][qr]
  const int qr = row & 63, qt = 16 + ((row >> 6) & 15), bh = row >> 10;
  const int b = bh >> 4, h = bh & 15;
  bf16x8 xa = *(const bf16x8*)&pacc[(size_t)row * 64 + d8 * 8];
  bf16x8 ya = *(const bf16x8*)&pacc[2097152 + (size_t)row * 64 + d8 * 8];
  const float inv = 1.f / (plsum[row] + plsum[32768 + row]);
  bf16x8 o;
  #pragma unroll
  for (int i = 0; i < 8; ++i)
    o[i] = f2b(((float)xa[i] + (float)ya[i]) * inv);
  *(bf16x8*)&attn_out[(size_t)(b * SEQ + qt * 64 + qr) * INNER + h * 64 + d8 * 8] = o;
}

// ---------------- layernorm over summed bf16 split-K partials ---------------
__global__ __launch_bounds__(256)
void layernorm_skb(const bf16_t* __restrict__ p0, const bf16_t* __restrict__ p1,
                   const float* __restrict__ g, float* __restrict__ out) {
  const int row = blockIdx.x;
  const int c = threadIdx.x * 4;
  bf16x4 a4 = *(const bf16x4*)&p0[(size_t)row * DIMX + c];
  bf16x4 b4 = *(const bf16x4*)&p1[(size_t)row * DIMX + c];
  const float vx = (float)a4[0] + (float)b4[0];
  const float vy = (float)a4[1] + (float)b4[1];
  const float vz = (float)a4[2] + (float)b4[2];
  const float vw = (float)a4[3] + (float)b4[3];
  float s = vx + vy + vz + vw;
  float q = vx * vx + vy * vy + vz * vz + vw * vw;
  #pragma unroll
  for (int o = 32; o > 0; o >>= 1) {
    s += __shfl_down(s, o);
    q += __shfl_down(q, o);
  }
  __shared__ float rs[4], rq[4];
  const int wid = threadIdx.x >> 6;
  if ((threadIdx.x & 63) == 0) { rs[wid] = s; rq[wid] = q; }
  __syncthreads();
  s = rs[0] + rs[1] + rs[2] + rs[3];
  q = rq[0] + rq[1] + rq[2] + rq[3];
  const float mean = s * (1.f / DIMX);
  const float var  = q * (1.f / DIMX) - mean * mean;
  const float inv  = rsqrtf(var + 1e-5f);
  float4 gv = *(const float4*)&g[c];
  float4 o4;
  o4.x = (vx - mean) * inv * gv.x;
  o4.y = (vy - mean) * inv * gv.y;
  o4.z = (vz - mean) * inv * gv.z;
  o4.w = (vw - mean) * inv * gv.w;
  *(float4*)&out[(size_t)row * DIMX + c] = o4;
}

// ---------------------------------------------------------------------------
extern "C" void kernel_launch(void* const* d_in, const int* in_sizes, int n_in,
                              void* d_out, int out_size, void* d_ws, size_t ws_size,
                              hipStream_t stream) {
  const float* x     = (const float*)d_in[0];
  // d_in[1] = mask: all-true in this problem; causal handled in-kernel.
  const float* w_qkv = (const float*)d_in[2];
  const float* w_out = (const float*)d_in[3];
  const float* g     = (const float*)d_in[4];

  char* ws = (char*)d_ws;
  const size_t MB = 1024 * 1024;
  bf16_t* xb     = (bf16_t*)(ws);              //  8 MB  [4096][1024] (pre-attn)
  bf16_t* wqkvT  = (bf16_t*)(ws + 8 * MB);     //  6 MB  [3072][1024] (pre-attn)
  bf16_t* woutT  = (bf16_t*)(ws + 14 * MB);    //  2 MB  [1024][1024]
  bf16_t* qkv    = (bf16_t*)(ws + 16 * MB);    // 24 MB  [4096][3072] (Q,K used)
  bf16_t* vt     = (bf16_t*)(ws + 40 * MB);    //  8 MB  [32*64][2048]
  bf16_t* attn_o = (bf16_t*)(ws + 48 * MB);    //  8 MB  [4096][1024]
  // aliases (regions dead by the time they're used):
  bf16_t* pacc   = (bf16_t*)(ws);              //  8 MB over xb (attn phase)
  float*  plsum  = (float*) (ws + 8 * MB);     // 256 KB over wqkvT (attn phase)
  bf16_t* partP  = (bf16_t*)(ws + 16 * MB);    // 16 MB over qkv (post-attn)

  prep_all<<<8192, 256, 0, stream>>>(x, w_qkv, w_out, xb, wqkvT, woutT);

  gemm_qkv<<<dim3(QKV_N / 128, NROWS / 128), 256, 0, stream>>>(
      xb, wqkvT, qkv, vt);

  attn_fa12<<<dim3(1024), 256, 0, stream>>>(qkv, vt, attn_o, pacc, plsum);
  attn_combine<<<dim3(1024), 256, 0, stream>>>(pacc, plsum, attn_o);

  gemm_osk<<<dim3(DIMX / 128, NROWS / 128, 2), 256, 0, stream>>>(
      attn_o, woutT, partP);

  layernorm_skb<<<NROWS, 256, 0, stream>>>(
      partP, partP + (size_t)NROWS * DIMX, g, (float*)d_out);
}

// Round 17
// 100.886 us; speedup vs baseline: 2.7902x; 1.0217x over previous
//
#include <hip/hip_runtime.h>
#include <hip/hip_bf16.h>

// ---------------------------------------------------------------------------
// Attention block: qkv = x@Wqkv ; flash causal attention ; out@Wout ; layernorm
// bf16 MFMA, fp32 accumulation.
// R16: V stored in PV-k-permuted order (p(j)=((j&15)>>2)*8+((j>>4)&1)*4+(j&3)
//      within each 32-j block) so the PV B-operand is ONE ds_read_b128 —
//      kills the vf concat (16 movs) + halves PV LDS issues. vt writer
//      (gemm_qkv epilogue) and PV reader changed in lockstep; STAGE/QK/mask
//      untouched. Rest identical to R15.
// ---------------------------------------------------------------------------

typedef __bf16 bf16_t;
typedef __bf16 bf16x8 __attribute__((ext_vector_type(8)));
typedef __bf16 bf16x4 __attribute__((ext_vector_type(4)));
typedef float  f32x4  __attribute__((ext_vector_type(4)));

#define DIMX   1024
#define HEADS  16
#define DHEAD  64
#define INNER  1024
#define SEQ    2048
#define BATCH  2
#define NROWS  (BATCH * SEQ)   // 4096
#define QKV_N  (3 * INNER)     // 3072
#define NQT    (SEQ / 64)      // 32 q-tiles of 64 rows
#define QK2SCALE 0.18033688011f   // 64^-0.5 * log2(e)

__device__ __forceinline__ bf16_t f2b(float f) { return (bf16_t)f; }

__device__ __forceinline__ float fexp2(float x) {
#if __has_builtin(__builtin_amdgcn_exp2f)
  return __builtin_amdgcn_exp2f(x);   // raw v_exp_f32
#else
  return exp2f(x);
#endif
}

// async global->LDS, 16B/lane. LDS dest = wave-uniform base + lane*16 (linear).
__device__ __forceinline__ void gload16(const bf16_t* g, bf16_t* s) {
  __builtin_amdgcn_global_load_lds(
      (const __attribute__((address_space(1))) unsigned int*)g,
      (__attribute__((address_space(3))) unsigned int*)s, 16, 0, 0);
}

__device__ __forceinline__ f32x4 mfma16(bf16x8 a, bf16x8 b, f32x4 c) {
  return __builtin_amdgcn_mfma_f32_16x16x32_bf16(a, b, c, 0, 0, 0);
}

// ---------------- prep: x->bf16 convert + both weight transposes ------------
__global__ __launch_bounds__(256)
void prep_all(const float* __restrict__ x, const float* __restrict__ w_qkv,
              const float* __restrict__ w_out, bf16_t* __restrict__ xb,
              bf16_t* __restrict__ wqkvT, bf16_t* __restrict__ woutT) {
  __shared__ float tile[32][33];
  const int bid = blockIdx.x;
  if (bid < 4096) {                       // convert x (fp32 -> bf16)
    const int i = bid * 256 + threadIdx.x;
    float4 v = *(const float4*)&x[(size_t)i * 4];
    bf16x4 o;
    o[0] = f2b(v.x); o[1] = f2b(v.y); o[2] = f2b(v.z); o[3] = f2b(v.w);
    *(bf16x4*)&xb[(size_t)i * 4] = o;
    return;
  }
  const float* in; bf16_t* out; int R, C, bx, by;
  if (bid < 4096 + 3072) {                // w_qkv [1024][3072] -> [3072][1024]
    const int t1 = bid - 4096;
    in = w_qkv; out = wqkvT; R = DIMX; C = QKV_N; bx = t1 % 96; by = t1 / 96;
  } else {                                // w_out [1024][1024] -> T
    const int t2 = bid - 7168;
    in = w_out; out = woutT; R = DIMX; C = DIMX; bx = t2 & 31; by = t2 >> 5;
  }
  const int c0 = bx * 32, r0 = by * 32;
  const int tx = threadIdx.x & 31, ty = threadIdx.x >> 5;   // 32 x 8
  #pragma unroll
  for (int i = 0; i < 32; i += 8)
    tile[ty + i][tx] = in[(size_t)(r0 + ty + i) * C + c0 + tx];
  __syncthreads();
  #pragma unroll
  for (int i = 0; i < 32; i += 8)
    out[(size_t)(c0 + ty + i) * R + r0 + tx] = f2b(tile[tx][ty + i]);
}

// ---------------- qkv GEMM with fused V-transpose ---------------------------
// C[M][N] = A[M][K] * Bt[N][K]^T, 128x128 tile, BK=64, 4 waves.
// Q/K tiles (n0<2048): bf16 store to qkv. V tiles (n0>=2048): transpose via
// the staging LDS and store C^T to vt with the PV-k-permutation baked in:
// within each 32-j block, element j lives at p(j)=((j&15)>>2)*8+((j>>4)&1)*4+(j&3).
__global__ __launch_bounds__(256)
void gemm_qkv(const bf16_t* __restrict__ A, const bf16_t* __restrict__ Bt,
              bf16_t* __restrict__ C, bf16_t* __restrict__ vt) {
  constexpr int BK = 64, K = 1024, N = QKV_N;
  __shared__ bf16_t smem[2 * 128 * BK];   // As | Bs ; reused as transpose buf
  bf16_t* As = smem;
  bf16_t* Bs = smem + 128 * BK;
  const int t = threadIdx.x;
  const int w = t >> 6, l = t & 63, lo = l & 15, hi = l >> 4;
  const int nwg = gridDim.x * gridDim.y;            // 768, %8==0
  int flat = blockIdx.y * gridDim.x + blockIdx.x;
  flat = (flat & 7) * (nwg >> 3) + (flat >> 3);     // XCD swizzle (bijective)
  const int m0 = (flat / gridDim.x) * 128, n0 = (flat % gridDim.x) * 128;
  const int wm = (w >> 1) * 64, wn = (w & 1) * 64;
  const int sl  = l >> 3;
  const int sgc = ((l & 7) ^ sl) * 8;               // r7-only involution
  const int r7  = lo & 7;
  f32x4 acc[4][4] = {};
  for (int k0 = 0; k0 < K; k0 += BK) {
    #pragma unroll
    for (int c = 0; c < 4; ++c) {
      const int rb = w * 32 + c * 8;
      gload16(&A [(size_t)(m0 + rb + sl) * K + k0 + sgc], &As[rb * BK + l * 8]);
      gload16(&Bt[(size_t)(n0 + rb + sl) * K + k0 + sgc], &Bs[rb * BK + l * 8]);
    }
    __syncthreads();
    #pragma unroll
    for (int kk = 0; kk < 2; ++kk) {
      bf16x8 af[4], bfr[4];
      #pragma unroll
      for (int mi = 0; mi < 4; ++mi)
        af[mi] = *(const bf16x8*)&As[(wm + mi * 16 + lo) * BK +
                                     (((kk * 4 + hi) ^ r7) << 3)];
      #pragma unroll
      for (int nj = 0; nj < 4; ++nj)
        bfr[nj] = *(const bf16x8*)&Bs[(wn + nj * 16 + lo) * BK +
                                      (((kk * 4 + hi) ^ r7) << 3)];
      __builtin_amdgcn_s_setprio(1);
      #pragma unroll
      for (int mi = 0; mi < 4; ++mi)
        #pragma unroll
        for (int nj = 0; nj < 4; ++nj)
          acc[mi][nj] = mfma16(af[mi], bfr[nj], acc[mi][nj]);
      __builtin_amdgcn_s_setprio(0);
    }
    __syncthreads();
  }
  if (n0 < 2 * INNER) {
    // ---- Q/K tiles: normal bf16 store
    #pragma unroll
    for (int mi = 0; mi < 4; ++mi)
      #pragma unroll
      for (int nj = 0; nj < 4; ++nj)
        #pragma unroll
        for (int r = 0; r < 4; ++r)
          C[(size_t)(m0 + wm + mi * 16 + hi * 4 + r) * N +
            n0 + wn + nj * 16 + lo] = f2b(acc[mi][nj][r]);
  } else {
    // ---- V tiles: transpose through LDS, store C^T to vt (permuted j).
    // T[c][j] granule g=j/4 (8B) lives at byte c*256 + ((g ^ (c&31))<<3).
    #pragma unroll
    for (int mi = 0; mi < 4; ++mi)
      #pragma unroll
      for (int nj = 0; nj < 4; ++nj) {
        const int cloc = wn + nj * 16 + lo;            // d-dim (col of C)
        const int g    = ((wm + mi * 16) >> 2) + hi;   // j-granule (row/4)
        bf16x4 pk;
        #pragma unroll
        for (int r = 0; r < 4; ++r) pk[r] = f2b(acc[mi][nj][r]);
        *(bf16x4*)((char*)smem + cloc * 256 + (((g ^ (cloc & 31))) << 3)) = pk;
      }
    __syncthreads();
    const int b  = m0 >> 11;           // m0 / SEQ
    const int j0 = m0 & (SEQ - 1);
    const int vrb = b * 1024 + (n0 - 2 * INNER);
    // thread's 8 j's = lo*8..+7; permuted positions: two b64 groups at
    // base jb32 = (lo>>2)*32, pA = (lo&1)*16 + ((lo>>1)&1)*4, pB = pA + 8.
    const int jb32 = (lo >> 2) * 32;
    const int pA   = (lo & 1) * 16 + ((lo >> 1) & 1) * 4;
    #pragma unroll
    for (int p = 0; p < 8; ++p) {
      const int c = p * 16 + w * 4 + hi;
      const int c31 = c & 31;
      bf16x4 a0 = *(const bf16x4*)((const char*)smem + c * 256 +
                                   (((2 * lo) ^ c31) << 3));
      bf16x4 a1 = *(const bf16x4*)((const char*)smem + c * 256 +
                                   (((2 * lo + 1) ^ c31) << 3));
      *(bf16x4*)&vt[(size_t)(vrb + c) * SEQ + j0 + jb32 + pA]     = a0;
      *(bf16x4*)&vt[(size_t)(vrb + c) * SEQ + j0 + jb32 + pA + 8] = a1;
    }
  }
}

// ---------------- out-projection GEMM, split-K=2, bf16 partials -------------
__global__ __launch_bounds__(256)
void gemm_osk(const bf16_t* __restrict__ A0, const bf16_t* __restrict__ Bt0,
              bf16_t* __restrict__ P) {
  constexpr int BK = 64, KH = 512, LDA = 1024, N = DIMX, M = NROWS;
  __shared__ bf16_t smem[2 * 128 * BK];
  bf16_t* As = smem;
  bf16_t* Bs = smem + 128 * BK;
  const int ks = blockIdx.z;
  const bf16_t* A  = A0  + ks * KH;
  const bf16_t* Bt = Bt0 + ks * KH;
  bf16_t* Cp = P + (size_t)ks * M * N;
  const int t = threadIdx.x;
  const int w = t >> 6, l = t & 63, lo = l & 15, hi = l >> 4;
  const int nwg = gridDim.x * gridDim.y;            // 256, %8==0
  int flat = blockIdx.y * gridDim.x + blockIdx.x;
  flat = (flat & 7) * (nwg >> 3) + (flat >> 3);
  const int m0 = (flat / gridDim.x) * 128, n0 = (flat % gridDim.x) * 128;
  const int wm = (w >> 1) * 64, wn = (w & 1) * 64;
  const int sl  = l >> 3;
  const int sgc = ((l & 7) ^ sl) * 8;
  const int r7  = lo & 7;
  f32x4 acc[4][4] = {};
  for (int k0 = 0; k0 < KH; k0 += BK) {
    #pragma unroll
    for (int c = 0; c < 4; ++c) {
      const int rb = w * 32 + c * 8;
      gload16(&A [(size_t)(m0 + rb + sl) * LDA + k0 + sgc], &As[rb * BK + l * 8]);
      gload16(&Bt[(size_t)(n0 + rb + sl) * LDA + k0 + sgc], &Bs[rb * BK + l * 8]);
    }
    __syncthreads();
    #pragma unroll
    for (int kk = 0; kk < 2; ++kk) {
      bf16x8 af[4], bfr[4];
      #pragma unroll
      for (int mi = 0; mi < 4; ++mi)
        af[mi] = *(const bf16x8*)&As[(wm + mi * 16 + lo) * BK +
                                     (((kk * 4 + hi) ^ r7) << 3)];
      #pragma unroll
      for (int nj = 0; nj < 4; ++nj)
        bfr[nj] = *(const bf16x8*)&Bs[(wn + nj * 16 + lo) * BK +
                                      (((kk * 4 + hi) ^ r7) << 3)];
      __builtin_amdgcn_s_setprio(1);
      #pragma unroll
      for (int mi = 0; mi < 4; ++mi)
        #pragma unroll
        for (int nj = 0; nj < 4; ++nj)
          acc[mi][nj] = mfma16(af[mi], bfr[nj], acc[mi][nj]);
      __builtin_amdgcn_s_setprio(0);
    }
    __syncthreads();
  }
  #pragma unroll
  for (int mi = 0; mi < 4; ++mi)
    #pragma unroll
    for (int nj = 0; nj < 4; ++nj)
      #pragma unroll
      for (int r = 0; r < 4; ++r)
        Cp[(size_t)(m0 + wm + mi * 16 + hi * 4 + r) * N +
           n0 + wn + nj * 16 + lo] = f2b(acc[mi][nj][r]);
}

// ---------------- flash causal attention ------------------------------------
// Balanced pair-split (1024 blocks). Swapped QK^T; PV via K=32 MFMA over
// paired jb's — B-operand is ONE b128 read thanks to the permuted vt layout.
// l-sum on the matrix pipe. Separate combine kernel (no in-kernel fences).
__global__ __launch_bounds__(256, 4)
void attn_fa14(const bf16_t* __restrict__ qkv, const bf16_t* __restrict__ vt,
               bf16_t* __restrict__ attn_out, bf16_t* __restrict__ pacc,
               float* __restrict__ plsum) {
  const int bx  = blockIdx.x;           // 1024
  const int xcd = bx & 7, idx = bx >> 3;
  const int bh  = xcd * 4 + (idx & 3);
  const int ta  = (idx >> 2) & 15;
  const int half = idx >> 6;            // 0 = X, 1 = Y
  const int tb  = NQT - 1 - ta;
  const int b = bh >> 4, h = bh & 15;
  const int t = threadIdx.x, w = t >> 6, l = t & 63, lo = l & 15, hi = l >> 4;

  __shared__ bf16_t Ks[2][64 * 64];     // 16 KB
  __shared__ bf16_t Vs[2][64 * 64];     // 16 KB

  const int srow = l >> 3;
  const int sgc  = ((l & 7) ^ srow) * 8;      // r7-only involution
  const size_t kgbase = (size_t)(b * SEQ) * QKV_N + INNER + h * 64;
  const size_t vgbase = (size_t)bh * 64 * SEQ;

  auto STAGE = [&](int ti, int buf) {
    const int j0 = ti * 64;
    #pragma unroll
    for (int c = 0; c < 2; ++c) {
      const int rb = w * 16 + c * 8;
      gload16(&qkv[kgbase + (size_t)(j0 + rb + srow) * QKV_N + sgc],
              &Ks[buf][rb * 64]);
      gload16(&vt[vgbase + (size_t)(rb + srow) * SEQ + j0 + sgc],
              &Vs[buf][rb * 64]);
    }
  };

  const int r7 = lo & 7;
  bf16x8 vone8;
  #pragma unroll
  for (int i = 0; i < 8; ++i) vone8[i] = f2b(1.0f);
  f32x4 acc[4];
  f32x4 acc_l;   // row hi*4+r: sum_j P[q=row][j], replicated across lo lanes

  auto SEG = [&](const int qt, const int t0, const int t1, const bool dmask) {
    const size_t qb = (size_t)(b * SEQ + qt * 64 + w * 16 + lo) * QKV_N + h * 64;
    bf16x8 qf0 = *(const bf16x8*)&qkv[qb + hi * 8];
    bf16x8 qf1 = *(const bf16x8*)&qkv[qb + 32 + hi * 8];
    #pragma unroll
    for (int i = 0; i < 8; ++i) {
      qf0[i] = f2b((float)qf0[i] * QK2SCALE);
      qf1[i] = f2b((float)qf1[i] * QK2SCALE);
    }
    const f32x4 fz = {};
    acc[0] = fz; acc[1] = fz; acc[2] = fz; acc[3] = fz;
    acc_l = fz;
    const int qrow = qt * 64 + w * 16 + lo;

    STAGE(t0, 0);
    for (int ti = t0; ti <= t1; ++ti) {
      const int buf = (ti - t0) & 1;
      __syncthreads();
      if (ti + 1 <= t1) STAGE(ti + 1, buf ^ 1);  // fly across compute
      const bool mB = dmask && (ti == t1);
      __builtin_amdgcn_s_setprio(1);
      #pragma unroll
      for (int pr = 0; pr < 2; ++pr) {           // jb pairs (0,1), (2,3)
        const int jb0 = pr * 2;
        if (!(mB && jb0 > w)) {
          bf16x8 pa;
          #pragma unroll
          for (int q = 0; q < 2; ++q) {
            const int jb = jb0 + q;
            f32x4 z = fz;
            if (!(mB && jb > w)) {
              const bf16_t* kp = &Ks[buf][(jb * 16 + lo) * 64];
              bf16x8 kf0 = *(const bf16x8*)&kp[(hi ^ r7) << 3];
              bf16x8 kf1 = *(const bf16x8*)&kp[((hi + 4) ^ r7) << 3];
              z = mfma16(kf0, qf0, z);
              z = mfma16(kf1, qf1, z);
            }
            #pragma unroll
            for (int r = 0; r < 4; ++r) {
              float pe = fexp2(z[r]);
              if (mB) {
                const int jglob = ti * 64 + jb * 16 + hi * 4 + r;
                if (jglob > qrow) pe = 0.f;      // causal
              }
              pa[q * 4 + r] = f2b(pe);
            }
          }
          // PV: B-operand is ONE b128 (vt layout matches pa's k-permutation)
          #pragma unroll
          for (int dj = 0; dj < 4; ++dj) {
            bf16x8 vf = *(const bf16x8*)&Vs[buf][(dj * 16 + lo) * 64 +
                        (((pr * 4 + hi) ^ r7) << 3)];
            acc[dj] = mfma16(pa, vf, acc[dj]);
          }
          acc_l = mfma16(pa, vone8, acc_l);
        }
      }
      __builtin_amdgcn_s_setprio(0);
    }
    __syncthreads();
  };

  const int prb = (bh * 16 + (tb - 16)) * 64;

  if (half == 0) {
    SEG(ta, 0, ta, true);
    #pragma unroll
    for (int r = 0; r < 4; ++r) {
      const float lr = 1.f / acc_l[r];
      #pragma unroll
      for (int dj = 0; dj < 4; ++dj)
        attn_out[(size_t)(b * SEQ + ta * 64 + w * 16 + hi * 4 + r) * INNER +
                 h * 64 + dj * 16 + lo] = f2b(acc[dj][r] * lr);
    }
    SEG(tb, 0, 15 - ta, false);
    #pragma unroll
    for (int dj = 0; dj < 4; ++dj)
      #pragma unroll
      for (int r = 0; r < 4; ++r)
        pacc[(size_t)(prb + w * 16 + hi * 4 + r) * 64 + dj * 16 + lo] =
            f2b(acc[dj][r]);
    if (lo == 0) {
      #pragma unroll
      for (int r = 0; r < 4; ++r)
        plsum[prb + w * 16 + hi * 4 + r] = acc_l[r];
    }
  } else {
    SEG(tb, 16 - ta, tb, true);
    #pragma unroll
    for (int dj = 0; dj < 4; ++dj)
      #pragma unroll
      for (int r = 0; r < 4; ++r)
        pacc[2097152 + (size_t)(prb + w * 16 + hi * 4 + r) * 64 + dj * 16 + lo] =
            f2b(acc[dj][r]);
    if (lo == 0) {
      #pragma unroll
      for (int r = 0; r < 4; ++r)
        plsum[32768 + prb + w * 16 + hi * 4 + r] = acc_l[r];
    }
  }
}

// ---------------- combine the two tb partials -------------------------------
__global__ __launch_bounds__(256)
void attn_combine(const bf16_t* __restrict__ pacc, const float* __restrict__ plsum,
                  bf16_t* __restrict__ attn_out) {
  const int g = blockIdx.x * 256 + threadIdx.x;   // 262144
  const int d8 = g & 7;
  const int row = g >> 3;                         // [bh][qt-16][qr]
  const int qr = row & 63, qt = 16 + ((row >> 6) & 15), bh = row >> 10;
  const int b = bh >> 4, h = bh & 15;
  bf16x8 xa = *(const bf16x8*)&pacc[(size_t)row * 64 + d8 * 8];
  bf16x8 ya = *(const bf16x8*)&pacc[2097152 + (size_t)row * 64 + d8 * 8];
  const float inv = 1.f / (plsum[row] + plsum[32768 + row]);
  bf16x8 o;
  #pragma unroll
  for (int i = 0; i < 8; ++i)
    o[i] = f2b(((float)xa[i] + (float)ya[i]) * inv);
  *(bf16x8*)&attn_out[(size_t)(b * SEQ + qt * 64 + qr) * INNER + h * 64 + d8 * 8] = o;
}

// ---------------- layernorm over summed bf16 split-K partials ---------------
__global__ __launch_bounds__(256)
void layernorm_skb(const bf16_t* __restrict__ p0, const bf16_t* __restrict__ p1,
                   const float* __restrict__ g, float* __restrict__ out) {
  const int row = blockIdx.x;
  const int c = threadIdx.x * 4;
  bf16x4 a4 = *(const bf16x4*)&p0[(size_t)row * DIMX + c];
  bf16x4 b4 = *(const bf16x4*)&p1[(size_t)row * DIMX + c];
  const float vx = (float)a4[0] + (float)b4[0];
  const float vy = (float)a4[1] + (float)b4[1];
  const float vz = (float)a4[2] + (float)b4[2];
  const float vw = (float)a4[3] + (float)b4[3];
  float s = vx + vy + vz + vw;
  float q = vx * vx + vy * vy + vz * vz + vw * vw;
  #pragma unroll
  for (int o = 32; o > 0; o >>= 1) {
    s += __shfl_down(s, o);
    q += __shfl_down(q, o);
  }
  __shared__ float rs[4], rq[4];
  const int wid = threadIdx.x >> 6;
  if ((threadIdx.x & 63) == 0) { rs[wid] = s; rq[wid] = q; }
  __syncthreads();
  s = rs[0] + rs[1] + rs[2] + rs[3];
  q = rq[0] + rq[1] + rq[2] + rq[3];
  const float mean = s * (1.f / DIMX);
  const float var  = q * (1.f / DIMX) - mean * mean;
  const float inv  = rsqrtf(var + 1e-5f);
  float4 gv = *(const float4*)&g[c];
  float4 o4;
  o4.x = (vx - mean) * inv * gv.x;
  o4.y = (vy - mean) * inv * gv.y;
  o4.z = (vz - mean) * inv * gv.z;
  o4.w = (vw - mean) * inv * gv.w;
  *(float4*)&out[(size_t)row * DIMX + c] = o4;
}

// ---------------------------------------------------------------------------
extern "C" void kernel_launch(void* const* d_in, const int* in_sizes, int n_in,
                              void* d_out, int out_size, void* d_ws, size_t ws_size,
                              hipStream_t stream) {
  const float* x     = (const float*)d_in[0];
  // d_in[1] = mask: all-true in this problem; causal handled in-kernel.
  const float* w_qkv = (const float*)d_in[2];
  const float* w_out = (const float*)d_in[3];
  const float* g     = (const float*)d_in[4];

  char* ws = (char*)d_ws;
  const size_t MB = 1024 * 1024;
  bf16_t* xb     = (bf16_t*)(ws);              //  8 MB  [4096][1024] (pre-attn)
  bf16_t* wqkvT  = (bf16_t*)(ws + 8 * MB);     //  6 MB  [3072][1024] (pre-attn)
  bf16_t* woutT  = (bf16_t*)(ws + 14 * MB);    //  2 MB  [1024][1024]
  bf16_t* qkv    = (bf16_t*)(ws + 16 * MB);    // 24 MB  [4096][3072] (Q,K used)
  bf16_t* vt     = (bf16_t*)(ws + 40 * MB);    //  8 MB  [32*64][2048]
  bf16_t* attn_o = (bf16_t*)(ws + 48 * MB);    //  8 MB  [4096][1024]
  // aliases (regions dead by the time they're used):
  bf16_t* pacc   = (bf16_t*)(ws);              //  8 MB over xb (attn phase)
  float*  plsum  = (float*) (ws + 8 * MB);     // 256 KB over wqkvT (attn phase)
  bf16_t* partP  = (bf16_t*)(ws + 16 * MB);    // 16 MB over qkv (post-attn)

  prep_all<<<8192, 256, 0, stream>>>(x, w_qkv, w_out, xb, wqkvT, woutT);

  gemm_qkv<<<dim3(QKV_N / 128, NROWS / 128), 256, 0, stream>>>(
      xb, wqkvT, qkv, vt);

  attn_fa14<<<dim3(1024), 256, 0, stream>>>(qkv, vt, attn_o, pacc, plsum);
  attn_combine<<<dim3(1024), 256, 0, stream>>>(pacc, plsum, attn_o);

  gemm_osk<<<dim3(DIMX / 128, NROWS / 128, 2), 256, 0, stream>>>(
      attn_o, woutT, partP);

  layernorm_skb<<<NROWS, 256, 0, stream>>>(
      partP, partP + (size_t)NROWS * DIMX, g, (float*)d_out);
}